// Round 1
// 1037.818 us; speedup vs baseline: 1.0182x; 1.0182x over previous
//
#include <hip/hip_runtime.h>
#include <hip/hip_bf16.h>

#define NPTS 8192
#define KN   32
#define DIM  256
#define DH   128
#define DOUT 512

typedef __attribute__((ext_vector_type(8))) short bf16x8;
typedef __attribute__((ext_vector_type(4))) float f32x4;

#define MFMA16(a, b, c) __builtin_amdgcn_mfma_f32_16x16x32_bf16((a), (b), (c), 0, 0, 0)

__device__ __forceinline__ short f2b(float f) {
    __hip_bfloat16 h = __float2bfloat16(f);
    return *reinterpret_cast<short*>(&h);
}

// ---------------- ws layout (bytes) ----------------
#define WSO_QATTN 0u                      // float[8192*256]
#define WSO_RES   8388608u                // float[8192*256]
#define WSO_WKT   16777216u               // short[65536]  -WkT[o][i]  (negated!)
#define WSO_WVT   16908288u               // short[65536]
#define WSO_G1T   17039360u               // short[65536]
#define WSO_G2T   17170432u               // short[65536]
#define WSO_D2T   17301504u               // short[32768]  d2T[o=256][i=128]
#define WSO_OWT   17367040u               // short[131072] owT[o=512][i=256]

// ================= prep 1: weights -> bf16 transposed =================
extern "C" __global__ __launch_bounds__(256)
void prep_w(const float* __restrict__ Wk, const float* __restrict__ Wv,
            const float* __restrict__ g1w, const float* __restrict__ g2w,
            const float* __restrict__ d2w, const float* __restrict__ ow,
            short* __restrict__ wkT, short* __restrict__ wvT,
            short* __restrict__ g1T, short* __restrict__ g2T,
            short* __restrict__ d2T, short* __restrict__ owT)
{
    const int idx = blockIdx.x * 256 + threadIdx.x;
    if (idx < 65536) {
        const int o = idx >> 8, i = idx & 255;
        wkT[idx] = f2b(-Wk[i * 256 + o]);          // NEGATED: h accumulates -k_attn
        wvT[idx] = f2b(Wv[i * 256 + o]);
        g1T[idx] = f2b(g1w[i * 256 + o]);
        g2T[idx] = f2b(g2w[i * 256 + o]);
    }
    if (idx < 32768) {
        const int o = idx >> 7, i = idx & 127;
        d2T[idx] = f2b(d2w[i * 256 + o]);
    }
    if (idx < 131072) {
        const int o = idx >> 8, i = idx & 255;
        owT[idx] = f2b(ow[i * 512 + o]);
    }
}

// ================= prep 2: q_attn = feats_q @ Wq (fp32) + xyz copy =================
extern "C" __global__ __launch_bounds__(256)
void prep_q(const float* __restrict__ feats_q, const float* __restrict__ Wq,
            const float* __restrict__ xyz_q, float* __restrict__ q_attn,
            float* __restrict__ out)
{
    const int b = blockIdx.x;
    const int t = threadIdx.x;
    if (b >= 1024) {                       // 96 blocks: xyz passthrough
        const int idx = (b - 1024) * 256 + t;
        out[idx] = xyz_q[idx];
        return;
    }
    __shared__ float s_q[8][256];
    for (int j = 0; j < 8; ++j)
        s_q[j][t] = feats_q[(size_t)(b * 8 + j) * 256 + t];
    __syncthreads();
    float acc[8] = {0.f, 0.f, 0.f, 0.f, 0.f, 0.f, 0.f, 0.f};
    for (int k = 0; k < 256; ++k) {
        const float wv = Wq[k * 256 + t];
        #pragma unroll
        for (int pt = 0; pt < 8; ++pt) acc[pt] = fmaf(s_q[pt][k], wv, acc[pt]);
    }
    #pragma unroll
    for (int pt = 0; pt < 8; ++pt)
        q_attn[(size_t)(b * 8 + pt) * 256 + t] = acc[pt];
}

// ================= main: one point per block, 4 column-slice waves ==============
// Shared XOR-swizzled h/t buffer (16 KB), fused accumulators, vp precomputed.
extern "C" __global__ __launch_bounds__(256, 3)
void ctb_main(const float* __restrict__ xyz_q, const float* __restrict__ xyz_kv,
              const float* __restrict__ feats_kv,
              const float* __restrict__ d1w, const float* __restrict__ d1b,
              const float* __restrict__ d2b, const float* __restrict__ g1b,
              const float* __restrict__ g2b,
              const float* __restrict__ q_attn,
              const short* __restrict__ wkTn, const short* __restrict__ wvT,
              const short* __restrict__ g1T, const short* __restrict__ g2T,
              const short* __restrict__ d2T,
              float* __restrict__ res_ws)
{
    __shared__ __align__(16) short s_h[KN * DIM];   // 16 KB shared h/t, XOR-swizzled
    const int w    = threadIdx.x >> 6;
    const int lane = threadIdx.x & 63;
    const int q    = lane >> 4;          // quad
    const int ln   = lane & 15;
    const int p    = blockIdx.x;         // one point per block
    const int colbase = 64 * w + ln;     // wave owns cols [64w, 64w+64)

    // ---- r1 = relu(rel @ d1w + d1b) as A-fragments (2 mt x 4 ks), bf16 ----
    bf16x8 a_r1[2][4];
    {
        float q0 = xyz_q[p * 3 + 0], q1 = xyz_q[p * 3 + 1], q2 = xyz_q[p * 3 + 2];
        float rel[2][3];
        #pragma unroll
        for (int mt = 0; mt < 2; ++mt) {
            const int m = 16 * mt + ln;
            const float* xk = xyz_kv + ((size_t)p * KN + m) * 3;
            rel[mt][0] = q0 - xk[0]; rel[mt][1] = q1 - xk[1]; rel[mt][2] = q2 - xk[2];
        }
        #pragma unroll
        for (int ks = 0; ks < 4; ++ks)
            #pragma unroll
            for (int j = 0; j < 8; ++j) {
                const int kd = 32 * ks + 8 * q + j;
                const float w0 = d1w[kd], w1 = d1w[DH + kd], w2 = d1w[2 * DH + kd];
                const float bb = d1b[kd];
                #pragma unroll
                for (int mt = 0; mt < 2; ++mt) {
                    const float v = fmaxf(fmaf(rel[mt][0], w0,
                                          fmaf(rel[mt][1], w1,
                                          fmaf(rel[mt][2], w2, bb))), 0.f);
                    a_r1[mt][ks][j] = f2b(v);
                }
            }
    }

    // ---- feats_kv[p] as A-fragments (2 mt x 8 ks), bf16 ----
    bf16x8 a_f[2][8];
    {
        const float* fp = feats_kv + (size_t)p * KN * DIM;
        #pragma unroll
        for (int mt = 0; mt < 2; ++mt) {
            const int m = 16 * mt + ln;
            #pragma unroll
            for (int ks = 0; ks < 8; ++ks) {
                const float4* src = (const float4*)(fp + m * DIM + 32 * ks + 8 * q);
                const float4 x = src[0], y = src[1];
                bf16x8 tv;
                tv[0] = f2b(x.x); tv[1] = f2b(x.y); tv[2] = f2b(x.z); tv[3] = f2b(x.w);
                tv[4] = f2b(y.x); tv[5] = f2b(y.y); tv[6] = f2b(y.z); tv[7] = f2b(y.w);
                a_f[mt][ks] = tv;
            }
        }
    }

    // ======== phase 1: vp = pos + v_attn (kept in regs); h = q + pos - k -> LDS ===
    f32x4 vp[2][4];                      // persists to phase 3
    {
        // vp init = d2b (pos bias)
        #pragma unroll
        for (int nt = 0; nt < 4; ++nt) {
            const float bb = d2b[colbase + 16 * nt];
            #pragma unroll
            for (int mt = 0; mt < 2; ++mt) vp[mt][nt] = (f32x4){bb, bb, bb, bb};
        }
        // pos MFMAs (K=128) -> vp   (a_r1 dies after this)
        #pragma unroll
        for (int ks = 0; ks < 4; ++ks) {
            const short* bp = d2T + 32 * ks + 8 * q;
            #pragma unroll
            for (int nt = 0; nt < 4; ++nt) {
                const bf16x8 bb = *(const bf16x8*)(bp + (colbase + 16 * nt) * DH);
                #pragma unroll
                for (int mt = 0; mt < 2; ++mt)
                    vp[mt][nt] = MFMA16(a_r1[mt][ks], bb, vp[mt][nt]);
            }
        }
        // hacc = vp + q_attn  (h shares the pos part)
        f32x4 hacc[2][4];
        #pragma unroll
        for (int nt = 0; nt < 4; ++nt) {
            const float qv = q_attn[(size_t)p * DIM + colbase + 16 * nt];
            #pragma unroll
            for (int mt = 0; mt < 2; ++mt) {
                hacc[mt][nt][0] = vp[mt][nt][0] + qv;
                hacc[mt][nt][1] = vp[mt][nt][1] + qv;
                hacc[mt][nt][2] = vp[mt][nt][2] + qv;
                hacc[mt][nt][3] = vp[mt][nt][3] + qv;
            }
        }
        // interleaved K=256 loops: hacc += a_f @ (-WkT);  vp += a_f @ WvT
        #pragma unroll
        for (int ks = 0; ks < 8; ++ks) {
            const short* bpk = wkTn + 32 * ks + 8 * q;
            const short* bpv = wvT  + 32 * ks + 8 * q;
            #pragma unroll
            for (int nt = 0; nt < 4; ++nt) {
                const int co = (colbase + 16 * nt) * DIM;
                const bf16x8 bk = *(const bf16x8*)(bpk + co);
                const bf16x8 bv = *(const bf16x8*)(bpv + co);
                #pragma unroll
                for (int mt = 0; mt < 2; ++mt) {
                    hacc[mt][nt] = MFMA16(a_f[mt][ks], bk, hacc[mt][nt]);
                    vp[mt][nt]   = MFMA16(a_f[mt][ks], bv, vp[mt][nt]);
                }
            }
        }
        // write h (bf16, XOR-swizzled)
        #pragma unroll
        for (int mt = 0; mt < 2; ++mt)
            #pragma unroll
            for (int nt = 0; nt < 4; ++nt)
                #pragma unroll
                for (int r = 0; r < 4; ++r) {
                    const int row = 16 * mt + 4 * q + r;
                    const int col = colbase + 16 * nt;
                    s_h[row * DIM + (col ^ ((row & 7) << 3))] = f2b(hacc[mt][nt][r]);
                }
    }
    __syncthreads();

    // ======== phase 2: t = relu(h @ g1 + g1b) -> LDS (overwrites h) ========
    {
        f32x4 tacc[2][4];
        #pragma unroll
        for (int nt = 0; nt < 4; ++nt) {
            const float bb = g1b[colbase + 16 * nt];
            #pragma unroll
            for (int mt = 0; mt < 2; ++mt) tacc[mt][nt] = (f32x4){bb, bb, bb, bb};
        }
        #pragma unroll
        for (int ks = 0; ks < 8; ++ks) {
            bf16x8 ah[2];
            #pragma unroll
            for (int mt = 0; mt < 2; ++mt) {
                const int row = 16 * mt + ln;
                ah[mt] = *(const bf16x8*)&s_h[row * DIM +
                                              ((32 * ks + 8 * q) ^ ((ln & 7) << 3))];
            }
            const short* bp = g1T + 32 * ks + 8 * q;
            #pragma unroll
            for (int nt = 0; nt < 4; ++nt) {
                const bf16x8 bb = *(const bf16x8*)(bp + (colbase + 16 * nt) * DIM);
                #pragma unroll
                for (int mt = 0; mt < 2; ++mt)
                    tacc[mt][nt] = MFMA16(ah[mt], bb, tacc[mt][nt]);
            }
        }
        __syncthreads();   // all waves done READING h
        #pragma unroll
        for (int mt = 0; mt < 2; ++mt)
            #pragma unroll
            for (int nt = 0; nt < 4; ++nt)
                #pragma unroll
                for (int r = 0; r < 4; ++r) {
                    const int row = 16 * mt + 4 * q + r;
                    const int col = colbase + 16 * nt;
                    s_h[row * DIM + (col ^ ((row & 7) << 3))] =
                        f2b(fmaxf(tacc[mt][nt][r], 0.f));
                }
    }
    __syncthreads();

    // ======== phase 3: ap = t@g2+g2b -> softmax_k -> res = sum ap*vp ========
    {
        f32x4 ap[2][4];
        #pragma unroll
        for (int nt = 0; nt < 4; ++nt) {
            const float bb = g2b[colbase + 16 * nt];
            #pragma unroll
            for (int mt = 0; mt < 2; ++mt) ap[mt][nt] = (f32x4){bb, bb, bb, bb};
        }
        #pragma unroll
        for (int ks = 0; ks < 8; ++ks) {
            bf16x8 at[2];
            #pragma unroll
            for (int mt = 0; mt < 2; ++mt) {
                const int row = 16 * mt + ln;
                at[mt] = *(const bf16x8*)&s_h[row * DIM +
                                              ((32 * ks + 8 * q) ^ ((ln & 7) << 3))];
            }
            const short* bp = g2T + 32 * ks + 8 * q;
            #pragma unroll
            for (int nt = 0; nt < 4; ++nt) {
                const bf16x8 bb = *(const bf16x8*)(bp + (colbase + 16 * nt) * DIM);
                #pragma unroll
                for (int mt = 0; mt < 2; ++mt)
                    ap[mt][nt] = MFMA16(at[mt], bb, ap[mt][nt]);
            }
        }

        // softmax over neighbors (rows): 8 local values + butterfly over lanes ^16,^32
        float stot[4];
        #pragma unroll
        for (int nt = 0; nt < 4; ++nt) {
            float m = -1e30f;
            #pragma unroll
            for (int mt = 0; mt < 2; ++mt)
                #pragma unroll
                for (int r = 0; r < 4; ++r) m = fmaxf(m, ap[mt][nt][r]);
            m = fmaxf(m, __shfl_xor(m, 16, 64));
            m = fmaxf(m, __shfl_xor(m, 32, 64));
            float s = 0.f;
            #pragma unroll
            for (int mt = 0; mt < 2; ++mt)
                #pragma unroll
                for (int r = 0; r < 4; ++r) {
                    const float e = __expf(ap[mt][nt][r] - m);
                    ap[mt][nt][r] = e;
                    s += e;
                }
            s += __shfl_xor(s, 16, 64);
            s += __shfl_xor(s, 32, 64);
            stot[nt] = s;
        }

        // weighted sum over rows with register-resident vp; quad 0 writes res
        #pragma unroll
        for (int nt = 0; nt < 4; ++nt) {
            float r = 0.f;
            #pragma unroll
            for (int mt = 0; mt < 2; ++mt)
                #pragma unroll
                for (int rr = 0; rr < 4; ++rr)
                    r = fmaf(ap[mt][nt][rr], vp[mt][nt][rr], r);
            r += __shfl_xor(r, 16, 64);
            r += __shfl_xor(r, 32, 64);
            if (q == 0)
                res_ws[(size_t)p * DIM + colbase + 16 * nt] = r / stot[nt];
        }
    }
}

// ================= out: res @ out_w + out_b (MFMA) =================
extern "C" __global__ __launch_bounds__(256, 2)
void ctb_out(const float* __restrict__ res_ws, const short* __restrict__ owT,
             const float* __restrict__ ob, float* __restrict__ out)
{
    __shared__ __align__(16) short s_a[32][264];
    const int t = threadIdx.x, w = t >> 6, lane = t & 63, q = lane >> 4, ln = lane & 15;
    const int rowbase = blockIdx.x * 32;

    {   // stage res rows -> bf16 LDS
        const int row = t >> 3;
        const int c0  = (t & 7) * 32;
        const float* src = res_ws + (size_t)(rowbase + row) * DIM + c0;
        #pragma unroll
        for (int j = 0; j < 32; j += 4) {
            const float4 v = *(const float4*)(src + j);
            s_a[row][c0 + j + 0] = f2b(v.x);
            s_a[row][c0 + j + 1] = f2b(v.y);
            s_a[row][c0 + j + 2] = f2b(v.z);
            s_a[row][c0 + j + 3] = f2b(v.w);
        }
    }
    __syncthreads();

    bf16x8 af[2][8];
    #pragma unroll
    for (int mt = 0; mt < 2; ++mt)
        #pragma unroll
        for (int ks = 0; ks < 8; ++ks)
            af[mt][ks] = *(const bf16x8*)&s_a[16 * mt + ln][32 * ks + 8 * q];

    const int colbase = 128 * w + ln;   // wave owns 128 of 512 cols
    f32x4 acc[2][8];
    #pragma unroll
    for (int nt = 0; nt < 8; ++nt) {
        const float bb = ob[colbase + 16 * nt];
        #pragma unroll
        for (int mt = 0; mt < 2; ++mt) acc[mt][nt] = (f32x4){bb, bb, bb, bb};
    }
    #pragma unroll
    for (int ks = 0; ks < 8; ++ks) {
        const short* bp = owT + 32 * ks + 8 * q;
        #pragma unroll
        for (int nt = 0; nt < 8; ++nt) {
            const bf16x8 bb = *(const bf16x8*)(bp + (colbase + 16 * nt) * DIM);
            #pragma unroll
            for (int mt = 0; mt < 2; ++mt)
                acc[mt][nt] = MFMA16(af[mt][ks], bb, acc[mt][nt]);
        }
    }
    float* o = out + (size_t)NPTS * 3;
    #pragma unroll
    for (int mt = 0; mt < 2; ++mt)
        #pragma unroll
        for (int nt = 0; nt < 8; ++nt)
            #pragma unroll
            for (int r = 0; r < 4; ++r) {
                const int row = 16 * mt + 4 * q + r;
                const int col = colbase + 16 * nt;
                o[(size_t)(rowbase + row) * DOUT + col] = acc[mt][nt][r];
            }
}

// ================= launch =================
extern "C" void kernel_launch(void* const* d_in, const int* in_sizes, int n_in,
                              void* d_out, int out_size, void* d_ws, size_t ws_size,
                              hipStream_t stream) {
    const float* xyz_q    = (const float*)d_in[0];
    const float* feats_q  = (const float*)d_in[1];
    const float* xyz_kv   = (const float*)d_in[2];
    const float* feats_kv = (const float*)d_in[3];
    const float* Wq       = (const float*)d_in[4];
    const float* Wk       = (const float*)d_in[5];
    const float* Wv       = (const float*)d_in[6];
    const float* d1w      = (const float*)d_in[7];
    const float* d1b      = (const float*)d_in[8];
    const float* d2w      = (const float*)d_in[9];
    const float* d2b      = (const float*)d_in[10];
    const float* g1w      = (const float*)d_in[11];
    const float* g1b      = (const float*)d_in[12];
    const float* g2w      = (const float*)d_in[13];
    const float* g2b      = (const float*)d_in[14];
    const float* ow       = (const float*)d_in[15];
    const float* ob       = (const float*)d_in[16];
    float* out = (float*)d_out;

    char* ws = (char*)d_ws;
    float* q_attn = (float*)(ws + WSO_QATTN);
    float* res_ws = (float*)(ws + WSO_RES);
    short* wkT    = (short*)(ws + WSO_WKT);
    short* wvT    = (short*)(ws + WSO_WVT);
    short* g1T    = (short*)(ws + WSO_G1T);
    short* g2T    = (short*)(ws + WSO_G2T);
    short* d2T    = (short*)(ws + WSO_D2T);
    short* owT    = (short*)(ws + WSO_OWT);

    prep_w<<<dim3(512), dim3(256), 0, stream>>>(Wk, Wv, g1w, g2w, d2w, ow,
                                                wkT, wvT, g1T, g2T, d2T, owT);
    prep_q<<<dim3(1120), dim3(256), 0, stream>>>(feats_q, Wq, xyz_q, q_attn, out);
    ctb_main<<<dim3(8192), dim3(256), 0, stream>>>(
        xyz_q, xyz_kv, feats_kv, d1w, d1b, d2b, g1b, g2b,
        q_attn, wkT, wvT, g1T, g2T, d2T, res_ws);
    ctb_out<<<dim3(256), dim3(256), 0, stream>>>(res_ws, owT, ob, out);
}

// Round 2
// 677.411 us; speedup vs baseline: 1.5599x; 1.5320x over previous
//
#include <hip/hip_runtime.h>
#include <hip/hip_bf16.h>

#define NPTS 8192
#define KN   32
#define DIM  256
#define DH   128
#define DOUT 512

typedef __attribute__((ext_vector_type(8))) short bf16x8;
typedef __attribute__((ext_vector_type(4))) short short4v;
typedef __attribute__((ext_vector_type(4))) float f32x4;

#define MFMA16(a, b, c) __builtin_amdgcn_mfma_f32_16x16x32_bf16((a), (b), (c), 0, 0, 0)

__device__ __forceinline__ short f2b(float f) {
    __hip_bfloat16 h = __float2bfloat16(f);
    return *reinterpret_cast<short*>(&h);
}

// ---------------- ws layout (bytes) ----------------
#define WSO_QATTN 0u                      // float[8192*256]
#define WSO_RES   8388608u                // float[8192*256]
#define WSO_WKT   16777216u               // short[65536]  -WkT[o][i]  (negated!)
#define WSO_WVT   16908288u               // short[65536]
#define WSO_G1T   17039360u               // short[65536]
#define WSO_G2T   17170432u               // short[65536]
#define WSO_D2T   17301504u               // short[32768]  d2T[o=256][i=128]
#define WSO_OWT   17367040u               // short[131072] owT[o=512][i=256]

// ================= prep 1: weights -> bf16 transposed =================
extern "C" __global__ __launch_bounds__(256)
void prep_w(const float* __restrict__ Wk, const float* __restrict__ Wv,
            const float* __restrict__ g1w, const float* __restrict__ g2w,
            const float* __restrict__ d2w, const float* __restrict__ ow,
            short* __restrict__ wkT, short* __restrict__ wvT,
            short* __restrict__ g1T, short* __restrict__ g2T,
            short* __restrict__ d2T, short* __restrict__ owT)
{
    const int idx = blockIdx.x * 256 + threadIdx.x;
    if (idx < 65536) {
        const int o = idx >> 8, i = idx & 255;
        wkT[idx] = f2b(-Wk[i * 256 + o]);          // NEGATED: h accumulates -k_attn
        wvT[idx] = f2b(Wv[i * 256 + o]);
        g1T[idx] = f2b(g1w[i * 256 + o]);
        g2T[idx] = f2b(g2w[i * 256 + o]);
    }
    if (idx < 32768) {
        const int o = idx >> 7, i = idx & 127;
        d2T[idx] = f2b(d2w[i * 256 + o]);
    }
    if (idx < 131072) {
        const int o = idx >> 8, i = idx & 255;
        owT[idx] = f2b(ow[i * 512 + o]);
    }
}

// ================= prep 2: q_attn = feats_q @ Wq (fp32), 16 rows/block ==========
extern "C" __global__ __launch_bounds__(256)
void prep_q(const float* __restrict__ feats_q, const float* __restrict__ Wq,
            const float* __restrict__ xyz_q, float* __restrict__ q_attn,
            float* __restrict__ out)
{
    const int b = blockIdx.x;
    const int t = threadIdx.x;
    if (b >= 512) {                        // 96 blocks: xyz passthrough
        const int idx = (b - 512) * 256 + t;
        out[idx] = xyz_q[idx];
        return;
    }
    __shared__ float s_q[16][256];
    for (int j = 0; j < 16; ++j)
        s_q[j][t] = feats_q[(size_t)(b * 16 + j) * 256 + t];
    __syncthreads();
    float acc[16];
    #pragma unroll
    for (int pt = 0; pt < 16; ++pt) acc[pt] = 0.f;
    for (int k = 0; k < 256; ++k) {
        const float wv = Wq[k * 256 + t];
        #pragma unroll
        for (int pt = 0; pt < 16; ++pt) acc[pt] = fmaf(s_q[pt][k], wv, acc[pt]);
    }
    #pragma unroll
    for (int pt = 0; pt < 16; ++pt)
        q_attn[(size_t)(b * 16 + pt) * 256 + t] = acc[pt];
}

// ================= main: 4 points/block, 8 waves, M=128, col slice 32/wave ======
// LDS (dynamic 64KB): F = shorts [0,16384)  : feats half, 128 rows x 128 k
//                     R1= shorts [16384,32768): r1, 128 rows x 128 k
//                     H = shorts [0,32768)  : h/t, 128 rows x 256   (overlays F,R1)
// all tiles XOR-swizzled: elem_idx = row*LD + (c ^ ((row&7)<<3))

#define STAGE_FEATS(koff)                                                         \
    {                                                                             \
        const float* fp_ = feats_kv + ((size_t)p0 * KN + srow) * DIM + (koff) +   \
                           scs * 32;                                              \
        _Pragma("unroll")                                                         \
        for (int j_ = 0; j_ < 8; ++j_) {                                          \
            const float4 v_ = *(const float4*)(fp_ + 4 * j_);                     \
            const int c2_ = scs * 32 + 4 * j_;                                    \
            short4v t_;                                                           \
            t_[0] = f2b(v_.x); t_[1] = f2b(v_.y);                                 \
            t_[2] = f2b(v_.z); t_[3] = f2b(v_.w);                                 \
            *(short4v*)&s_lds[srow * 128 + (c2_ ^ ((srow & 7) << 3))] = t_;       \
        }                                                                         \
    }

extern "C" __global__ __launch_bounds__(512, 2)
void ctb_main(const float* __restrict__ xyz_q, const float* __restrict__ xyz_kv,
              const float* __restrict__ feats_kv,
              const float* __restrict__ d1w, const float* __restrict__ d1b,
              const float* __restrict__ d2b, const float* __restrict__ g1b,
              const float* __restrict__ g2b,
              const float* __restrict__ q_attn,
              const short* __restrict__ wkTn, const short* __restrict__ wvT,
              const short* __restrict__ g1T, const short* __restrict__ g2T,
              const short* __restrict__ d2T,
              float* __restrict__ res_ws)
{
    extern __shared__ short s_lds[];
    const int t    = threadIdx.x;
    const int w    = t >> 6;
    const int lane = t & 63;
    const int q    = lane >> 4;
    const int ln   = lane & 15;
    const int p0   = blockIdx.x * 4;
    const int colbase = 32 * w + ln;

    const int srow = t >> 2;       // 0..127 staging row
    const int scs  = t & 3;        // 0..3   staging col chunk

    // ---------- stage feats half-0 (k 0..127) + r1 (cooperative) ----------
    STAGE_FEATS(0);
    {
        const int pt = srow >> 5;
        const float qx = xyz_q[(p0 + pt) * 3 + 0];
        const float qy = xyz_q[(p0 + pt) * 3 + 1];
        const float qz = xyz_q[(p0 + pt) * 3 + 2];
        const float* xk = xyz_kv + ((size_t)p0 * KN + srow) * 3;
        const float rx = qx - xk[0], ry = qy - xk[1], rz = qz - xk[2];
        #pragma unroll
        for (int j = 0; j < 32; ++j) {
            const int c = scs * 32 + j;
            const float v = fmaxf(fmaf(rx, d1w[c],
                                  fmaf(ry, d1w[DH + c],
                                  fmaf(rz, d1w[2 * DH + c], d1b[c]))), 0.f);
            s_lds[16384 + srow * 128 + (c ^ ((srow & 7) << 3))] = f2b(v);
        }
    }
    __syncthreads();

    // ---------- phase 1: vp = d2b + pos + v ; h = vp_pos + q - k -> H ----------
    f32x4 vp[8][2];
    #pragma unroll
    for (int nt = 0; nt < 2; ++nt) {
        const float bb = d2b[colbase + 16 * nt];
        #pragma unroll
        for (int mt = 0; mt < 8; ++mt) vp[mt][nt] = (f32x4){bb, bb, bb, bb};
    }
    #pragma unroll
    for (int ks = 0; ks < 4; ++ks) {                 // pos: K=128, A from R1
        bf16x8 ar[8];
        #pragma unroll
        for (int mt = 0; mt < 8; ++mt) {
            const int row = 16 * mt + ln;
            ar[mt] = *(const bf16x8*)&s_lds[16384 + row * 128 +
                                            ((32 * ks + 8 * q) ^ ((row & 7) << 3))];
        }
        #pragma unroll
        for (int nt = 0; nt < 2; ++nt) {
            const bf16x8 bb = *(const bf16x8*)(d2T + (colbase + 16 * nt) * DH +
                                               32 * ks + 8 * q);
            #pragma unroll
            for (int mt = 0; mt < 8; ++mt)
                vp[mt][nt] = MFMA16(ar[mt], bb, vp[mt][nt]);
        }
    }
    f32x4 hacc[8][2];                                // h starts from pos + q_attn
    #pragma unroll
    for (int nt = 0; nt < 2; ++nt)
        #pragma unroll
        for (int pt = 0; pt < 4; ++pt) {
            const float qv = q_attn[(size_t)(p0 + pt) * DIM + colbase + 16 * nt];
            #pragma unroll
            for (int m2 = 0; m2 < 2; ++m2) {
                const int mt = 2 * pt + m2;
                #pragma unroll
                for (int r = 0; r < 4; ++r) hacc[mt][nt][r] = vp[mt][nt][r] + qv;
            }
        }
    #pragma unroll
    for (int half = 0; half < 2; ++half) {           // kv: K=256 in 2 staged halves
        if (half) {
            __syncthreads();
            STAGE_FEATS(128);
            __syncthreads();
        }
        #pragma unroll
        for (int ksl = 0; ksl < 4; ++ksl) {
            const int ks = 4 * half + ksl;
            bf16x8 af[8];
            #pragma unroll
            for (int mt = 0; mt < 8; ++mt) {
                const int row = 16 * mt + ln;
                af[mt] = *(const bf16x8*)&s_lds[row * 128 +
                                                ((32 * ksl + 8 * q) ^ ((row & 7) << 3))];
            }
            #pragma unroll
            for (int nt = 0; nt < 2; ++nt) {
                const int co = (colbase + 16 * nt) * DIM + 32 * ks + 8 * q;
                const bf16x8 bk = *(const bf16x8*)(wkTn + co);
                const bf16x8 bv = *(const bf16x8*)(wvT + co);
                #pragma unroll
                for (int mt = 0; mt < 8; ++mt) {
                    hacc[mt][nt] = MFMA16(af[mt], bk, hacc[mt][nt]);
                    vp[mt][nt]   = MFMA16(af[mt], bv, vp[mt][nt]);
                }
            }
        }
    }
    __syncthreads();                                 // F, R1 now dead
    #pragma unroll
    for (int mt = 0; mt < 8; ++mt)                   // write h -> H (overlays F,R1)
        #pragma unroll
        for (int nt = 0; nt < 2; ++nt)
            #pragma unroll
            for (int r = 0; r < 4; ++r) {
                const int row = 16 * mt + 4 * q + r;
                const int col = colbase + 16 * nt;
                s_lds[row * 256 + (col ^ ((row & 7) << 3))] = f2b(hacc[mt][nt][r]);
            }
    __syncthreads();

    // ---------- phase 2: t = relu(h @ g1 + g1b) -> H (in place) ----------
    {
        f32x4 tacc[8][2];
        #pragma unroll
        for (int nt = 0; nt < 2; ++nt) {
            const float bb = g1b[colbase + 16 * nt];
            #pragma unroll
            for (int mt = 0; mt < 8; ++mt) tacc[mt][nt] = (f32x4){bb, bb, bb, bb};
        }
        #pragma unroll
        for (int ks = 0; ks < 8; ++ks) {
            bf16x8 ah[8];
            #pragma unroll
            for (int mt = 0; mt < 8; ++mt) {
                const int row = 16 * mt + ln;
                ah[mt] = *(const bf16x8*)&s_lds[row * 256 +
                                                ((32 * ks + 8 * q) ^ ((row & 7) << 3))];
            }
            #pragma unroll
            for (int nt = 0; nt < 2; ++nt) {
                const bf16x8 bb = *(const bf16x8*)(g1T + (colbase + 16 * nt) * DIM +
                                                   32 * ks + 8 * q);
                #pragma unroll
                for (int mt = 0; mt < 8; ++mt)
                    tacc[mt][nt] = MFMA16(ah[mt], bb, tacc[mt][nt]);
            }
        }
        __syncthreads();                             // all reads of h done
        #pragma unroll
        for (int mt = 0; mt < 8; ++mt)
            #pragma unroll
            for (int nt = 0; nt < 2; ++nt)
                #pragma unroll
                for (int r = 0; r < 4; ++r) {
                    const int row = 16 * mt + 4 * q + r;
                    const int col = colbase + 16 * nt;
                    s_lds[row * 256 + (col ^ ((row & 7) << 3))] =
                        f2b(fmaxf(tacc[mt][nt][r], 0.f));
                }
        __syncthreads();
    }

    // ---------- phase 3: ap = t@g2+g2b -> softmax_k -> res = sum ap*vp ----------
    {
        f32x4 ap[8][2];
        #pragma unroll
        for (int nt = 0; nt < 2; ++nt) {
            const float bb = g2b[colbase + 16 * nt];
            #pragma unroll
            for (int mt = 0; mt < 8; ++mt) ap[mt][nt] = (f32x4){bb, bb, bb, bb};
        }
        #pragma unroll
        for (int ks = 0; ks < 8; ++ks) {
            bf16x8 at[8];
            #pragma unroll
            for (int mt = 0; mt < 8; ++mt) {
                const int row = 16 * mt + ln;
                at[mt] = *(const bf16x8*)&s_lds[row * 256 +
                                                ((32 * ks + 8 * q) ^ ((row & 7) << 3))];
            }
            #pragma unroll
            for (int nt = 0; nt < 2; ++nt) {
                const bf16x8 bb = *(const bf16x8*)(g2T + (colbase + 16 * nt) * DIM +
                                                   32 * ks + 8 * q);
                #pragma unroll
                for (int mt = 0; mt < 8; ++mt)
                    ap[mt][nt] = MFMA16(at[mt], bb, ap[mt][nt]);
            }
        }

        // softmax over each point's 32 neighbors: rows {2pt,2pt+1} x q x r
        float stot[4][2];
        #pragma unroll
        for (int pt = 0; pt < 4; ++pt)
            #pragma unroll
            for (int nt = 0; nt < 2; ++nt) {
                float m = -1e30f;
                #pragma unroll
                for (int m2 = 0; m2 < 2; ++m2)
                    #pragma unroll
                    for (int r = 0; r < 4; ++r)
                        m = fmaxf(m, ap[2 * pt + m2][nt][r]);
                m = fmaxf(m, __shfl_xor(m, 16, 64));
                m = fmaxf(m, __shfl_xor(m, 32, 64));
                float s = 0.f;
                #pragma unroll
                for (int m2 = 0; m2 < 2; ++m2)
                    #pragma unroll
                    for (int r = 0; r < 4; ++r) {
                        const float e = __expf(ap[2 * pt + m2][nt][r] - m);
                        ap[2 * pt + m2][nt][r] = e;
                        s += e;
                    }
                s += __shfl_xor(s, 16, 64);
                s += __shfl_xor(s, 32, 64);
                stot[pt][nt] = s;
            }

        // weighted sum with register-resident vp; quad 0 writes res
        #pragma unroll
        for (int pt = 0; pt < 4; ++pt)
            #pragma unroll
            for (int nt = 0; nt < 2; ++nt) {
                float racc = 0.f;
                #pragma unroll
                for (int m2 = 0; m2 < 2; ++m2)
                    #pragma unroll
                    for (int r = 0; r < 4; ++r)
                        racc = fmaf(ap[2 * pt + m2][nt][r], vp[2 * pt + m2][nt][r],
                                    racc);
                racc += __shfl_xor(racc, 16, 64);
                racc += __shfl_xor(racc, 32, 64);
                if (q == 0)
                    res_ws[(size_t)(p0 + pt) * DIM + colbase + 16 * nt] =
                        racc / stot[pt][nt];
            }
    }
}

// ================= out: res @ out_w + out_b (MFMA), 64 rows/block ===============
extern "C" __global__ __launch_bounds__(256, 2)
void ctb_out(const float* __restrict__ res_ws, const short* __restrict__ owT,
             const float* __restrict__ ob, float* __restrict__ out)
{
    __shared__ __align__(16) short s_a[64 * 256];    // 32KB, XOR-swizzled
    const int t = threadIdx.x, w = t >> 6, lane = t & 63, q = lane >> 4, ln = lane & 15;
    const int rowbase = blockIdx.x * 64;

    {   // stage res rows -> bf16 LDS (swizzled)
        const int row = t >> 2;
        const int cs  = t & 3;
        const float* src = res_ws + (size_t)(rowbase + row) * DIM + cs * 64;
        #pragma unroll
        for (int j = 0; j < 16; ++j) {
            const float4 v = *(const float4*)(src + 4 * j);
            const int c = cs * 64 + 4 * j;
            short4v sv;
            sv[0] = f2b(v.x); sv[1] = f2b(v.y); sv[2] = f2b(v.z); sv[3] = f2b(v.w);
            *(short4v*)&s_a[row * 256 + (c ^ ((row & 7) << 3))] = sv;
        }
    }
    __syncthreads();

    const int colbase = 128 * w + ln;   // wave owns 128 of 512 cols
    f32x4 acc[4][8];
    #pragma unroll
    for (int nt = 0; nt < 8; ++nt) {
        const float bb = ob[colbase + 16 * nt];
        #pragma unroll
        for (int mt = 0; mt < 4; ++mt) acc[mt][nt] = (f32x4){bb, bb, bb, bb};
    }
    #pragma unroll
    for (int ks = 0; ks < 8; ++ks) {
        bf16x8 af[4];
        #pragma unroll
        for (int mt = 0; mt < 4; ++mt) {
            const int row = 16 * mt + ln;
            af[mt] = *(const bf16x8*)&s_a[row * 256 +
                                          ((32 * ks + 8 * q) ^ ((row & 7) << 3))];
        }
        #pragma unroll
        for (int nt = 0; nt < 8; ++nt) {
            const bf16x8 bb = *(const bf16x8*)(owT + (colbase + 16 * nt) * DIM +
                                               32 * ks + 8 * q);
            #pragma unroll
            for (int mt = 0; mt < 4; ++mt)
                acc[mt][nt] = MFMA16(af[mt], bb, acc[mt][nt]);
        }
    }
    float* o = out + (size_t)NPTS * 3;
    #pragma unroll
    for (int mt = 0; mt < 4; ++mt)
        #pragma unroll
        for (int nt = 0; nt < 8; ++nt)
            #pragma unroll
            for (int r = 0; r < 4; ++r) {
                const int row = 16 * mt + 4 * q + r;
                const int col = colbase + 16 * nt;
                o[(size_t)(rowbase + row) * DOUT + col] = acc[mt][nt][r];
            }
}

// ================= launch =================
extern "C" void kernel_launch(void* const* d_in, const int* in_sizes, int n_in,
                              void* d_out, int out_size, void* d_ws, size_t ws_size,
                              hipStream_t stream) {
    const float* xyz_q    = (const float*)d_in[0];
    const float* feats_q  = (const float*)d_in[1];
    const float* xyz_kv   = (const float*)d_in[2];
    const float* feats_kv = (const float*)d_in[3];
    const float* Wq       = (const float*)d_in[4];
    const float* Wk       = (const float*)d_in[5];
    const float* Wv       = (const float*)d_in[6];
    const float* d1w      = (const float*)d_in[7];
    const float* d1b      = (const float*)d_in[8];
    const float* d2w      = (const float*)d_in[9];
    const float* d2b      = (const float*)d_in[10];
    const float* g1w      = (const float*)d_in[11];
    const float* g1b      = (const float*)d_in[12];
    const float* g2w      = (const float*)d_in[13];
    const float* g2b      = (const float*)d_in[14];
    const float* ow       = (const float*)d_in[15];
    const float* ob       = (const float*)d_in[16];
    float* out = (float*)d_out;

    char* ws = (char*)d_ws;
    float* q_attn = (float*)(ws + WSO_QATTN);
    float* res_ws = (float*)(ws + WSO_RES);
    short* wkT    = (short*)(ws + WSO_WKT);
    short* wvT    = (short*)(ws + WSO_WVT);
    short* g1T    = (short*)(ws + WSO_G1T);
    short* g2T    = (short*)(ws + WSO_G2T);
    short* d2T    = (short*)(ws + WSO_D2T);
    short* owT    = (short*)(ws + WSO_OWT);

    prep_w<<<dim3(512), dim3(256), 0, stream>>>(Wk, Wv, g1w, g2w, d2w, ow,
                                                wkT, wvT, g1T, g2T, d2T, owT);
    prep_q<<<dim3(608), dim3(256), 0, stream>>>(feats_q, Wq, xyz_q, q_attn, out);
    ctb_main<<<dim3(2048), dim3(512), 65536, stream>>>(
        xyz_q, xyz_kv, feats_kv, d1w, d1b, d2b, g1b, g2b,
        q_attn, wkT, wvT, g1T, g2T, d2T, res_ws);
    ctb_out<<<dim3(128), dim3(256), 0, stream>>>(res_ws, owT, ob, out);
}